// Round 11
// baseline (203.236 us; speedup 1.0000x reference)
//
#include <hip/hip_runtime.h>
#include <hip/hip_cooperative_groups.h>
#include <math.h>

namespace cg = cooperative_groups;

// SSAaligner: s[i,j] = -sum_d |x[i,d]-y[j,d]|, x from z_x(D,N), y from z_y(D,M)
// a = softmax_rows(s), b = softmax_cols(s), u = a+b-a*b, out = sum(u*s)/sum(u)
// D=256, N=M=1024. fp32 in, fp32 scalar out.
//
// R11: ONE cooperative kernel (R8's best-measured structure, fused end-to-end).
// Phase 1 = R8 scompute (16r x 128c x 256d tiles, 4r x 2c/thread, y double-
// buffered 16-d LDS chunks, fused row/col partial stats) with acc kept in
// registers -- S is NEVER materialized (saves 4 MB write + 4 MB read + final
// kernel). grid.sync(); Phase 2 = 20 blocks fold partials -> rmax/rsum/
// cmax/csum. grid.sync(); Phase 3 = u-formula on register acc, block reduce,
// atomic, ticket-divide. 512 blocks x 256 thr = 2 blocks/CU co-resident
// (36 KB LDS, ~60 VGPR). ~42 us of total is the harness's 268 MB ws-poison
// fill (untouchable).

#define DD 256
#define NN 1024
#define NQ 256         // float4 per row

__device__ __forceinline__ float waveMax(float v) {
  #pragma unroll
  for (int off = 32; off; off >>= 1) v = fmaxf(v, __shfl_xor(v, off, 64));
  return v;
}
__device__ __forceinline__ float waveSum(float v) {
  #pragma unroll
  for (int off = 32; off; off >>= 1) v += __shfl_xor(v, off, 64);
  return v;
}

// ---------------- fast path: single cooperative kernel ----------------

__global__ __launch_bounds__(256, 2)
void fused_kernel(const float* __restrict__ zx, const float* __restrict__ zy,
                  float* __restrict__ pRM, float* __restrict__ pRL,
                  float* __restrict__ pCM, float* __restrict__ pCL,
                  float* __restrict__ rmax, float* __restrict__ rsum,
                  float* __restrict__ cmax, float* __restrict__ csum,
                  float* __restrict__ accum, float* __restrict__ out) {
  cg::grid_group grid = cg::this_grid();
  const int bid = blockIdx.x;       // 0..511
  const int bx  = bid & 7;          // j-chunk 0..7 (128 cols)
  const int by  = bid >> 3;         // i-tile 0..63 (16 rows)
  const int i0  = by * 16;
  const int t   = threadIdx.x;
  const int w   = t >> 6;           // wave 0..3
  const int ln  = t & 63;           // lane

  __shared__ float xs[DD][16];      // 16 KB, xs[d][r] — wave-uniform reads
  __shared__ float ys[2][16][128];  // 16 KB, double-buffered 16-d y chunks
  __shared__ float cmS[4][128];     // 2 KB (reused in phases 2/3)
  __shared__ float clS[4][128];     // 2 KB

  if (bid == 0 && t == 0) {
    accum[0] = 0.f; accum[1] = 0.f; ((unsigned int*)accum)[2] = 0u;
  }

  const float4* __restrict__ X4 = (const float4*)zx;
  const float4* __restrict__ Y4 = (const float4*)zy;

  // ---- phase 1: distance tile, acc in registers (R8 scompute body) ----
  #pragma unroll
  for (int i = 0; i < 4; ++i) {
    const int k = t + i * 256;
    const int d = k >> 2, rq = k & 3;
    *(float4*)&xs[d][rq * 4] = X4[d * NQ + by * 4 + rq];
  }
  const int sd = t >> 4;            // d-row 0..15
  const int sq = t & 15;            // quad 0..15 (plus +16)
  const int jq0 = bx * 32;
  *(float4*)&ys[0][sd][sq * 4]        = Y4[sd * NQ + jq0 + sq];
  *(float4*)&ys[0][sd][(sq + 16) * 4] = Y4[sd * NQ + jq0 + sq + 16];
  __syncthreads();

  float acc[4][2];
  #pragma unroll
  for (int r = 0; r < 4; ++r) { acc[r][0] = 0.f; acc[r][1] = 0.f; }

  #pragma unroll 1
  for (int n = 0; n < DD / 16; ++n) {
    const int buf = n & 1;
    float4 p0, p1;
    if (n < DD / 16 - 1) {
      p0 = Y4[(16 * (n + 1) + sd) * NQ + jq0 + sq];
      p1 = Y4[(16 * (n + 1) + sd) * NQ + jq0 + sq + 16];
    }
    #pragma unroll
    for (int dd = 0; dd < 16; ++dd) {
      const int d = n * 16 + dd;
      const float4 xv = *(const float4*)&xs[d][w * 4];
      const float2 yv = *(const float2*)&ys[buf][dd][ln * 2];
      acc[0][0] += fabsf(xv.x - yv.x); acc[0][1] += fabsf(xv.x - yv.y);
      acc[1][0] += fabsf(xv.y - yv.x); acc[1][1] += fabsf(xv.y - yv.y);
      acc[2][0] += fabsf(xv.z - yv.x); acc[2][1] += fabsf(xv.z - yv.y);
      acc[3][0] += fabsf(xv.w - yv.x); acc[3][1] += fabsf(xv.w - yv.y);
    }
    if (n < DD / 16 - 1) {
      *(float4*)&ys[buf ^ 1][sd][sq * 4]        = p0;
      *(float4*)&ys[buf ^ 1][sd][(sq + 16) * 4] = p1;
    }
    __syncthreads();
  }

  // row-stat partials over this 128-col chunk (rows are per-wave)
  #pragma unroll
  for (int r = 0; r < 4; ++r) {
    float m = fmaxf(-acc[r][0], -acc[r][1]);
    m = waveMax(m);
    float l = __expf(-acc[r][0] - m) + __expf(-acc[r][1] - m);
    l = waveSum(l);
    if (ln == 0) {
      pRM[bx * NN + i0 + w * 4 + r] = m;
      pRL[bx * NN + i0 + w * 4 + r] = l;
    }
  }

  // col-stat partials over this 16-row tile
  #pragma unroll
  for (int c = 0; c < 2; ++c) {
    float m = fmaxf(fmaxf(-acc[0][c], -acc[1][c]), fmaxf(-acc[2][c], -acc[3][c]));
    float l = __expf(-acc[0][c] - m) + __expf(-acc[1][c] - m) +
              __expf(-acc[2][c] - m) + __expf(-acc[3][c] - m);
    cmS[w][ln * 2 + c] = m;
    clS[w][ln * 2 + c] = l;
  }
  __syncthreads();
  if (t < 128) {
    const int j = t;
    const float m0 = cmS[0][j], m1 = cmS[1][j], m2 = cmS[2][j], m3 = cmS[3][j];
    const float M = fmaxf(fmaxf(m0, m1), fmaxf(m2, m3));
    const float L = clS[0][j] * __expf(m0 - M) + clS[1][j] * __expf(m1 - M) +
                    clS[2][j] * __expf(m2 - M) + clS[3][j] * __expf(m3 - M);
    pCM[by * NN + bx * 128 + j] = M;
    pCL[by * NN + bx * 128 + j] = L;
  }

  grid.sync();

  // ---- phase 2: fold partials (blocks 0..19; others pass through) ----
  if (bid < 16) {
    __syncthreads();                // cmS/clS reuse safety
    const int c = t & 63;
    const int g = t >> 6;           // fold group 0..3 (16 stripes each)
    const int j = bid * 64 + c;
    float m = -1e30f;
    #pragma unroll
    for (int k = 0; k < 16; ++k) m = fmaxf(m, pCM[(g * 16 + k) * NN + j]);
    float l = 0.f;
    #pragma unroll
    for (int k = 0; k < 16; ++k)
      l += __expf(pCM[(g * 16 + k) * NN + j] - m) * pCL[(g * 16 + k) * NN + j];
    cmS[g][c] = m; clS[g][c] = l;
    __syncthreads();
    if (g == 0) {
      const float m0 = cmS[0][c], m1 = cmS[1][c], m2 = cmS[2][c], m3 = cmS[3][c];
      const float M = fmaxf(fmaxf(m0, m1), fmaxf(m2, m3));
      const float L = clS[0][c] * __expf(m0 - M) + clS[1][c] * __expf(m1 - M) +
                      clS[2][c] * __expf(m2 - M) + clS[3][c] * __expf(m3 - M);
      cmax[j] = M; csum[j] = L;
    }
  } else if (bid < 20) {
    const int r = (bid - 16) * 256 + t;
    float mk[8], lk[8];
    #pragma unroll
    for (int k = 0; k < 8; ++k) { mk[k] = pRM[k * NN + r]; lk[k] = pRL[k * NN + r]; }
    float m = mk[0];
    #pragma unroll
    for (int k = 1; k < 8; ++k) m = fmaxf(m, mk[k]);
    float l = 0.f;
    #pragma unroll
    for (int k = 0; k < 8; ++k) l += lk[k] * __expf(mk[k] - m);
    rmax[r] = m; rsum[r] = l;
  }

  grid.sync();

  // ---- phase 3: u-formula on register acc, reduce, ticket-divide ----
  const float2 cmv = ((const float2*)cmax)[bx * 64 + ln];   // my 2 cols
  const float2 csv = ((const float2*)csum)[bx * 64 + ln];
  float un = 0.f, ud = 0.f;
  #pragma unroll
  for (int r = 0; r < 4; ++r) {
    const int row = i0 + w * 4 + r;
    const float rm = rmax[row];
    const float ri = 1.f / rsum[row];
    {
      const float s = -acc[r][0];
      const float a = __expf(s - rm) * ri;
      const float b = __expf(s - cmv.x) / csv.x;
      const float u = a + b - a * b;
      un += u * s; ud += u;
    }
    {
      const float s = -acc[r][1];
      const float a = __expf(s - rm) * ri;
      const float b = __expf(s - cmv.y) / csv.y;
      const float u = a + b - a * b;
      un += u * s; ud += u;
    }
  }
  un = waveSum(un); ud = waveSum(ud);
  __syncthreads();                  // protect cmS reuse
  if (ln == 0) { cmS[0][w] = un; clS[0][w] = ud; }
  __syncthreads();
  if (t == 0) {
    atomicAdd(&accum[0], cmS[0][0] + cmS[0][1] + cmS[0][2] + cmS[0][3]);
    atomicAdd(&accum[1], clS[0][0] + clS[0][1] + clS[0][2] + clS[0][3]);
    __threadfence();
    unsigned int* cnt = (unsigned int*)accum + 2;
    const unsigned int old = atomicAdd(cnt, 1u);
    if (old == gridDim.x - 1) {
      const float n = atomicAdd(&accum[0], 0.f);
      const float d = atomicAdd(&accum[1], 0.f);
      out[0] = n / d;
    }
  }
}

// ---------------- fallback path (R2, ws >= ~148 KB, proven) ----------------

#define TJ  128
#define NCH (NN / TJ)
#define BLK 256

__global__ __launch_bounds__(BLK)
void stats2_kernel(const float* __restrict__ zx, const float* __restrict__ zy,
                   float* __restrict__ partM, float* __restrict__ partS) {
  const int side = blockIdx.z;
  const float* __restrict__ X = side ? zy : zx;
  const float* __restrict__ Y = side ? zx : zy;
  const int j0 = blockIdx.x * TJ;
  const int i0 = blockIdx.y * 8;
  const int t  = threadIdx.x;
  const int rg = t >> 5;
  const int c  = t & 31;

  __shared__ float xs[8 * DD];
  for (int k = t; k < 8 * DD; k += BLK)
    xs[k] = X[(k >> 3) * NN + i0 + (k & 7)];
  __syncthreads();

  const float4* __restrict__ Y4 = (const float4*)Y;
  const int yb = (j0 >> 2) + c;
  float4 acc = make_float4(0.f, 0.f, 0.f, 0.f);
  #pragma unroll 8
  for (int d = 0; d < DD; ++d) {
    const float4 yv = Y4[d * NQ + yb];
    const float xv = xs[d * 8 + rg];
    acc.x += fabsf(xv - yv.x);
    acc.y += fabsf(xv - yv.y);
    acc.z += fabsf(xv - yv.z);
    acc.w += fabsf(xv - yv.w);
  }

  float m = fmaxf(fmaxf(-acc.x, -acc.y), fmaxf(-acc.z, -acc.w));
  #pragma unroll
  for (int off = 16; off > 0; off >>= 1) m = fmaxf(m, __shfl_xor(m, off, 32));
  float p = __expf(-acc.x - m) + __expf(-acc.y - m) +
            __expf(-acc.z - m) + __expf(-acc.w - m);
  #pragma unroll
  for (int off = 16; off > 0; off >>= 1) p += __shfl_xor(p, off, 32);

  if (c == 0) {
    const int idx = side * (NCH * NN) + blockIdx.x * NN + (i0 + rg);
    partM[idx] = m;
    partS[idx] = p;
  }
}

__global__ __launch_bounds__(BLK)
void combine_kernel_fb(const float* __restrict__ partM, const float* __restrict__ partS,
                       float* __restrict__ rmax, float* __restrict__ rsum,
                       float* __restrict__ cmax, float* __restrict__ csum,
                       float* __restrict__ accum) {
  const int gid = blockIdx.x * BLK + threadIdx.x;
  if (gid == 0) { accum[0] = 0.f; accum[1] = 0.f; }
  const int sd = gid >> 10;
  const int i  = gid & (NN - 1);
  float mk[NCH], sk[NCH];
  #pragma unroll
  for (int k = 0; k < NCH; ++k) {
    mk[k] = partM[sd * (NCH * NN) + k * NN + i];
    sk[k] = partS[sd * (NCH * NN) + k * NN + i];
  }
  float m = mk[0];
  #pragma unroll
  for (int k = 1; k < NCH; ++k) m = fmaxf(m, mk[k]);
  float s = 0.f;
  #pragma unroll
  for (int k = 0; k < NCH; ++k) s += __expf(mk[k] - m) * sk[k];
  if (sd == 0) { rmax[i] = m; rsum[i] = s; }
  else         { cmax[i] = m; csum[i] = s; }
}

__global__ __launch_bounds__(BLK)
void final2_kernel(const float* __restrict__ zx, const float* __restrict__ zy,
                   const float* __restrict__ rmax, const float* __restrict__ rsum,
                   const float* __restrict__ cmax, const float* __restrict__ csum,
                   float* __restrict__ accum) {
  const int j0 = blockIdx.x * TJ;
  const int i0 = blockIdx.y * 8;
  const int t  = threadIdx.x;
  const int rg = t >> 5;
  const int c  = t & 31;

  __shared__ float xs[8 * DD];
  __shared__ float redn[4], redd[4];
  for (int k = t; k < 8 * DD; k += BLK)
    xs[k] = zx[(k >> 3) * NN + i0 + (k & 7)];
  __syncthreads();

  const float4* __restrict__ Y4 = (const float4*)zy;
  const int yb = (j0 >> 2) + c;
  float4 acc = make_float4(0.f, 0.f, 0.f, 0.f);
  #pragma unroll 8
  for (int d = 0; d < DD; ++d) {
    const float4 yv = Y4[d * NQ + yb];
    const float xv = xs[d * 8 + rg];
    acc.x += fabsf(xv - yv.x);
    acc.y += fabsf(xv - yv.y);
    acc.z += fabsf(xv - yv.z);
    acc.w += fabsf(xv - yv.w);
  }

  const int i = i0 + rg;
  const float rm = rmax[i];
  const float ri = 1.f / rsum[i];
  const float4 cm = ((const float4*)cmax)[yb];
  const float4 cs = ((const float4*)csum)[yb];

  float un = 0.f, ud = 0.f;
  {
    const float s = -acc.x;
    const float a = __expf(s - rm) * ri;
    const float b = __expf(s - cm.x) / cs.x;
    const float u = a + b - a * b;
    un += u * s; ud += u;
  }
  {
    const float s = -acc.y;
    const float a = __expf(s - rm) * ri;
    const float b = __expf(s - cm.y) / cs.y;
    const float u = a + b - a * b;
    un += u * s; ud += u;
  }
  {
    const float s = -acc.z;
    const float a = __expf(s - rm) * ri;
    const float b = __expf(s - cm.z) / cs.z;
    const float u = a + b - a * b;
    un += u * s; ud += u;
  }
  {
    const float s = -acc.w;
    const float a = __expf(s - rm) * ri;
    const float b = __expf(s - cm.w) / cs.w;
    const float u = a + b - a * b;
    un += u * s; ud += u;
  }

  un = waveSum(un); ud = waveSum(ud);
  if ((t & 63) == 0) { redn[t >> 6] = un; redd[t >> 6] = ud; }
  __syncthreads();
  if (t == 0) {
    atomicAdd(&accum[0], redn[0] + redn[1] + redn[2] + redn[3]);
    atomicAdd(&accum[1], redd[0] + redd[1] + redd[2] + redd[3]);
  }
}

__global__ void finalize_kernel(const float* __restrict__ accum, float* __restrict__ out) {
  out[0] = accum[0] / accum[1];
}

// ---------------------------------------------------------------------------

extern "C" void kernel_launch(void* const* d_in, const int* in_sizes, int n_in,
                              void* d_out, int out_size, void* d_ws, size_t ws_size,
                              hipStream_t stream) {
  const float* zx = (const float*)d_in[0];   // (1, D, N): X[d*N + i]
  const float* zy = (const float*)d_in[1];   // (1, D, M): Y[d*M + j]
  float* ws  = (float*)d_ws;
  float* out = (float*)d_out;

  // fast-path ws layout (floats): ~600 KB (no S slab!)
  float* accum = ws;                         // [0]=num, [1]=den, [2]=ticket
  float* pRM   = ws + 16;                    // 8 * 1024
  float* pRL   = pRM + 8 * NN;
  float* pCM   = pRL + 8 * NN;               // 64 * 1024
  float* pCL   = pCM + 64 * NN;
  float* rmax  = pCL + 64 * NN;
  float* rsum  = rmax + NN;
  float* cmax  = rsum + NN;
  float* csum  = cmax + NN;
  const size_t need = (size_t)((csum + NN) - ws) * sizeof(float);

  if (ws_size >= need) {
    void* args[] = {
      (void*)&zx, (void*)&zy,
      (void*)&pRM, (void*)&pRL, (void*)&pCM, (void*)&pCL,
      (void*)&rmax, (void*)&rsum, (void*)&cmax, (void*)&csum,
      (void*)&accum, (void*)&out
    };
    hipLaunchCooperativeKernel((void*)fused_kernel, dim3(512), dim3(256),
                               args, 0, stream);
  } else {
    // R2 fallback (~148 KB)
    float* partM = ws + 16;
    float* partS = partM + 2 * NCH * NN;
    float* frmax = partS + 2 * NCH * NN;
    float* frsum = frmax + NN;
    float* fcmax = frsum + NN;
    float* fcsum = fcmax + NN;
    dim3 sgrid(NCH, NN / 8, 2);
    stats2_kernel<<<sgrid, BLK, 0, stream>>>(zx, zy, partM, partS);
    combine_kernel_fb<<<(2 * NN) / BLK, BLK, 0, stream>>>(partM, partS,
                                                          frmax, frsum, fcmax, fcsum, accum);
    dim3 fgrid(NCH, NN / 8);
    final2_kernel<<<fgrid, BLK, 0, stream>>>(zx, zy, frmax, frsum, fcmax, fcsum, accum);
    finalize_kernel<<<1, 1, 0, stream>>>(accum, out);
  }
}

// Round 12
// 107.417 us; speedup vs baseline: 1.8920x; 1.8920x over previous
//
#include <hip/hip_runtime.h>
#include <math.h>

// SSAaligner: s[i,j] = -sum_d |x[i,d]-y[j,d]|, x from z_x(D,N), y from z_y(D,M)
// a = softmax_rows(s), b = softmax_cols(s), u = a+b-a*b, out = sum(u*s)/sum(u)
// D=256, N=M=1024. fp32 in, fp32 scalar out.
//
// R12: R8 structure (best measured: 105.5 us) with ONE change: the x operand
// no longer goes through LDS. x is wave-uniform; the row base is scalarized
// with readfirstlane so the per-d x read compiles to s_load (scalar cache) or
// a broadcast vector load -- either way off the LDS pipe. LDS now carries only
// the y stream (b64/wave-d = 56 LDS cyc/CU-d < 64 VALU cyc) -> scompute is
// VALU-bound by construction. R11's cooperative fusion regressed badly
// (grid.sync ~50us on 8 XCDs) and is abandoned. ~42 us of total is the
// harness's 268 MB ws-poison fill (untouchable).

#define DD 256
#define NN 1024
#define NQ 256         // float4 per row

__device__ __forceinline__ float waveMax(float v) {
  #pragma unroll
  for (int off = 32; off; off >>= 1) v = fmaxf(v, __shfl_xor(v, off, 64));
  return v;
}
__device__ __forceinline__ float waveSum(float v) {
  #pragma unroll
  for (int off = 32; off; off >>= 1) v += __shfl_xor(v, off, 64);
  return v;
}

// ---------------- fast path ----------------

// Grid (8 j-chunks, 64 i-tiles) = 512 blocks, 256 threads, 2 blocks/CU.
// Tile 16r x 128c x 256d. Wave w owns rows i0+4w..+3 (x via scalar loads);
// lane ln owns cols j0+2ln..+1 (y via LDS b64). 16-d y double-buffer.
__global__ __launch_bounds__(256, 2)
void scompute_kernel(const float* __restrict__ zx, const float* __restrict__ zy,
                     float* __restrict__ S,
                     float* __restrict__ pRM, float* __restrict__ pRL,
                     float* __restrict__ pCM, float* __restrict__ pCL) {
  const int bx = blockIdx.x;        // j-chunk 0..7 (128 cols)
  const int by = blockIdx.y;        // i-tile 0..63 (16 rows)
  const int i0 = by * 16;
  const int t  = threadIdx.x;
  const int w  = t >> 6;            // wave 0..3
  const int ln = t & 63;            // lane

  __shared__ float ys[2][16][128];  // 16 KB, double-buffered 16-d y chunks
  __shared__ float cmS[4][128];     // 2 KB
  __shared__ float clS[4][128];     // 2 KB

  const float4* __restrict__ Y4 = (const float4*)zy;

  // x base: wave-uniform, scalarized -> per-d reads become scalar/broadcast
  // loads (off the LDS pipe). Xq[d * NQ] = x[d][rows i0+4w .. i0+4w+3].
  const int rowq = __builtin_amdgcn_readfirstlane((i0 + w * 4) >> 2);
  const float4* __restrict__ Xq = (const float4*)zx + rowq;

  // stage y chunk 0: 16 d x 32 quads = 512 float4, 2 per thread
  const int sd = t >> 4;            // d-row 0..15
  const int sq = t & 15;            // quad 0..15 (plus +16)
  const int jq0 = bx * 32;
  *(float4*)&ys[0][sd][sq * 4]        = Y4[sd * NQ + jq0 + sq];
  *(float4*)&ys[0][sd][(sq + 16) * 4] = Y4[sd * NQ + jq0 + sq + 16];
  __syncthreads();

  float acc[4][2];
  #pragma unroll
  for (int r = 0; r < 4; ++r) { acc[r][0] = 0.f; acc[r][1] = 0.f; }

  #pragma unroll 1
  for (int n = 0; n < DD / 16; ++n) {
    const int buf = n & 1;
    float4 p0, p1;
    if (n < DD / 16 - 1) {
      p0 = Y4[(16 * (n + 1) + sd) * NQ + jq0 + sq];
      p1 = Y4[(16 * (n + 1) + sd) * NQ + jq0 + sq + 16];
    }
    #pragma unroll
    for (int dd = 0; dd < 16; ++dd) {
      const int d = n * 16 + dd;
      const float4 xv = Xq[d * NQ];                 // scalar/broadcast load
      const float2 yv = *(const float2*)&ys[buf][dd][ln * 2];
      acc[0][0] += fabsf(xv.x - yv.x); acc[0][1] += fabsf(xv.x - yv.y);
      acc[1][0] += fabsf(xv.y - yv.x); acc[1][1] += fabsf(xv.y - yv.y);
      acc[2][0] += fabsf(xv.z - yv.x); acc[2][1] += fabsf(xv.z - yv.y);
      acc[3][0] += fabsf(xv.w - yv.x); acc[3][1] += fabsf(xv.w - yv.y);
    }
    if (n < DD / 16 - 1) {
      *(float4*)&ys[buf ^ 1][sd][sq * 4]        = p0;
      *(float4*)&ys[buf ^ 1][sd][(sq + 16) * 4] = p1;
    }
    __syncthreads();
  }

  // ---- epilogue (R8) ----
  float2* __restrict__ S2 = (float2*)S;
  #pragma unroll
  for (int r = 0; r < 4; ++r)
    S2[(i0 + w * 4 + r) * (NN / 2) + bx * 64 + ln] = make_float2(acc[r][0], acc[r][1]);

  // row-stat partials over this 128-col chunk (rows are per-wave)
  #pragma unroll
  for (int r = 0; r < 4; ++r) {
    float m = fmaxf(-acc[r][0], -acc[r][1]);
    m = waveMax(m);
    float l = __expf(-acc[r][0] - m) + __expf(-acc[r][1] - m);
    l = waveSum(l);
    if (ln == 0) {
      pRM[bx * NN + i0 + w * 4 + r] = m;
      pRL[bx * NN + i0 + w * 4 + r] = l;
    }
  }

  // col-stat partials over this 16-row tile
  #pragma unroll
  for (int c = 0; c < 2; ++c) {
    float m = fmaxf(fmaxf(-acc[0][c], -acc[1][c]), fmaxf(-acc[2][c], -acc[3][c]));
    float l = __expf(-acc[0][c] - m) + __expf(-acc[1][c] - m) +
              __expf(-acc[2][c] - m) + __expf(-acc[3][c] - m);
    cmS[w][ln * 2 + c] = m;
    clS[w][ln * 2 + c] = l;
  }
  __syncthreads();
  if (t < 128) {
    const int j = t;
    const float m0 = cmS[0][j], m1 = cmS[1][j], m2 = cmS[2][j], m3 = cmS[3][j];
    const float M = fmaxf(fmaxf(m0, m1), fmaxf(m2, m3));
    const float L = clS[0][j] * __expf(m0 - M) + clS[1][j] * __expf(m1 - M) +
                    clS[2][j] * __expf(m2 - M) + clS[3][j] * __expf(m3 - M);
    pCM[by * NN + bx * 128 + j] = M;
    pCL[by * NN + bx * 128 + j] = L;
  }
}

// 20 blocks x 256 (R8). Blocks 0..15: columns (64 cols; 4 fold-groups of 16
// partials, LDS-merged). Blocks 16..19: rows (256 rows each, fold 8).
__global__ __launch_bounds__(256)
void combine_kernel(const float* __restrict__ pRM, const float* __restrict__ pRL,
                    const float* __restrict__ pCM, const float* __restrict__ pCL,
                    float* __restrict__ rmax, float* __restrict__ rsum,
                    float* __restrict__ cmax, float* __restrict__ csum,
                    float* __restrict__ accum) {
  const int b = blockIdx.x, t = threadIdx.x;
  if (b == 0 && t == 0) {
    accum[0] = 0.f; accum[1] = 0.f; ((unsigned int*)accum)[2] = 0u;
  }
  if (b < 16) {
    __shared__ float sm[4][64], sl[4][64];
    const int c = t & 63;
    const int g = t >> 6;
    const int j = b * 64 + c;
    float m = -1e30f;
    #pragma unroll
    for (int k = 0; k < 16; ++k) m = fmaxf(m, pCM[(g * 16 + k) * NN + j]);
    float l = 0.f;
    #pragma unroll
    for (int k = 0; k < 16; ++k)
      l += __expf(pCM[(g * 16 + k) * NN + j] - m) * pCL[(g * 16 + k) * NN + j];
    sm[g][c] = m; sl[g][c] = l;
    __syncthreads();
    if (g == 0) {
      const float m0 = sm[0][c], m1 = sm[1][c], m2 = sm[2][c], m3 = sm[3][c];
      const float M = fmaxf(fmaxf(m0, m1), fmaxf(m2, m3));
      const float L = sl[0][c] * __expf(m0 - M) + sl[1][c] * __expf(m1 - M) +
                      sl[2][c] * __expf(m2 - M) + sl[3][c] * __expf(m3 - M);
      cmax[j] = M; csum[j] = L;
    }
  } else {
    const int r = (b - 16) * 256 + t;
    float mk[8], lk[8];
    #pragma unroll
    for (int k = 0; k < 8; ++k) { mk[k] = pRM[k * NN + r]; lk[k] = pRL[k * NN + r]; }
    float m = mk[0];
    #pragma unroll
    for (int k = 1; k < 8; ++k) m = fmaxf(m, mk[k]);
    float l = 0.f;
    #pragma unroll
    for (int k = 0; k < 8; ++k) l += lk[k] * __expf(mk[k] - m);
    rmax[r] = m; rsum[r] = l;
  }
}

// 512 blocks x 2 rows (R8): u = a+b-a*b, reduce, atomic; LAST block divides.
__global__ __launch_bounds__(256)
void final_kernel(const float* __restrict__ S,
                  const float* __restrict__ rmax, const float* __restrict__ rsum,
                  const float* __restrict__ cmax, const float* __restrict__ csum,
                  float* __restrict__ accum, float* __restrict__ out) {
  __shared__ float redn[4], redd[4];
  const int t = threadIdx.x;
  const int row0 = blockIdx.x * 2;
  const float4* S4 = (const float4*)S;
  const float4 cm = ((const float4*)cmax)[t];
  const float4 cs = ((const float4*)csum)[t];
  float un = 0.f, ud = 0.f;
  #pragma unroll
  for (int r = 0; r < 2; ++r) {
    const int row = row0 + r;
    const float rm = rmax[row];
    const float ri = 1.f / rsum[row];
    const float4 p = S4[row * NQ + t];
    {
      const float s = -p.x;
      const float a = __expf(s - rm) * ri;
      const float b = __expf(s - cm.x) / cs.x;
      const float u = a + b - a * b;
      un += u * s; ud += u;
    }
    {
      const float s = -p.y;
      const float a = __expf(s - rm) * ri;
      const float b = __expf(s - cm.y) / cs.y;
      const float u = a + b - a * b;
      un += u * s; ud += u;
    }
    {
      const float s = -p.z;
      const float a = __expf(s - rm) * ri;
      const float b = __expf(s - cm.z) / cs.z;
      const float u = a + b - a * b;
      un += u * s; ud += u;
    }
    {
      const float s = -p.w;
      const float a = __expf(s - rm) * ri;
      const float b = __expf(s - cm.w) / cs.w;
      const float u = a + b - a * b;
      un += u * s; ud += u;
    }
  }
  un = waveSum(un); ud = waveSum(ud);
  if ((t & 63) == 0) { redn[t >> 6] = un; redd[t >> 6] = ud; }
  __syncthreads();
  if (t == 0) {
    atomicAdd(&accum[0], redn[0] + redn[1] + redn[2] + redn[3]);
    atomicAdd(&accum[1], redd[0] + redd[1] + redd[2] + redd[3]);
    __threadfence();
    unsigned int* cnt = (unsigned int*)accum + 2;
    const unsigned int old = atomicAdd(cnt, 1u);
    if (old == gridDim.x - 1) {
      const float n = atomicAdd(&accum[0], 0.f);
      const float d = atomicAdd(&accum[1], 0.f);
      out[0] = n / d;
    }
  }
}

// ---------------- fallback path (R2, ws >= ~148 KB, proven) ----------------

#define TJ  128
#define NCH (NN / TJ)
#define BLK 256

__global__ __launch_bounds__(BLK)
void stats2_kernel(const float* __restrict__ zx, const float* __restrict__ zy,
                   float* __restrict__ partM, float* __restrict__ partS) {
  const int side = blockIdx.z;
  const float* __restrict__ X = side ? zy : zx;
  const float* __restrict__ Y = side ? zx : zy;
  const int j0 = blockIdx.x * TJ;
  const int i0 = blockIdx.y * 8;
  const int t  = threadIdx.x;
  const int rg = t >> 5;
  const int c  = t & 31;

  __shared__ float xs[8 * DD];
  for (int k = t; k < 8 * DD; k += BLK)
    xs[k] = X[(k >> 3) * NN + i0 + (k & 7)];
  __syncthreads();

  const float4* __restrict__ Y4 = (const float4*)Y;
  const int yb = (j0 >> 2) + c;
  float4 acc = make_float4(0.f, 0.f, 0.f, 0.f);
  #pragma unroll 8
  for (int d = 0; d < DD; ++d) {
    const float4 yv = Y4[d * NQ + yb];
    const float xv = xs[d * 8 + rg];
    acc.x += fabsf(xv - yv.x);
    acc.y += fabsf(xv - yv.y);
    acc.z += fabsf(xv - yv.z);
    acc.w += fabsf(xv - yv.w);
  }

  float m = fmaxf(fmaxf(-acc.x, -acc.y), fmaxf(-acc.z, -acc.w));
  #pragma unroll
  for (int off = 16; off > 0; off >>= 1) m = fmaxf(m, __shfl_xor(m, off, 32));
  float p = __expf(-acc.x - m) + __expf(-acc.y - m) +
            __expf(-acc.z - m) + __expf(-acc.w - m);
  #pragma unroll
  for (int off = 16; off > 0; off >>= 1) p += __shfl_xor(p, off, 32);

  if (c == 0) {
    const int idx = side * (NCH * NN) + blockIdx.x * NN + (i0 + rg);
    partM[idx] = m;
    partS[idx] = p;
  }
}

__global__ __launch_bounds__(BLK)
void combine_kernel_fb(const float* __restrict__ partM, const float* __restrict__ partS,
                       float* __restrict__ rmax, float* __restrict__ rsum,
                       float* __restrict__ cmax, float* __restrict__ csum,
                       float* __restrict__ accum) {
  const int gid = blockIdx.x * BLK + threadIdx.x;
  if (gid == 0) { accum[0] = 0.f; accum[1] = 0.f; }
  const int sd = gid >> 10;
  const int i  = gid & (NN - 1);
  float mk[NCH], sk[NCH];
  #pragma unroll
  for (int k = 0; k < NCH; ++k) {
    mk[k] = partM[sd * (NCH * NN) + k * NN + i];
    sk[k] = partS[sd * (NCH * NN) + k * NN + i];
  }
  float m = mk[0];
  #pragma unroll
  for (int k = 1; k < NCH; ++k) m = fmaxf(m, mk[k]);
  float s = 0.f;
  #pragma unroll
  for (int k = 0; k < NCH; ++k) s += __expf(mk[k] - m) * sk[k];
  if (sd == 0) { rmax[i] = m; rsum[i] = s; }
  else         { cmax[i] = m; csum[i] = s; }
}

__global__ __launch_bounds__(BLK)
void final2_kernel(const float* __restrict__ zx, const float* __restrict__ zy,
                   const float* __restrict__ rmax, const float* __restrict__ rsum,
                   const float* __restrict__ cmax, const float* __restrict__ csum,
                   float* __restrict__ accum) {
  const int j0 = blockIdx.x * TJ;
  const int i0 = blockIdx.y * 8;
  const int t  = threadIdx.x;
  const int rg = t >> 5;
  const int c  = t & 31;

  __shared__ float xs[8 * DD];
  __shared__ float redn[4], redd[4];
  for (int k = t; k < 8 * DD; k += BLK)
    xs[k] = zx[(k >> 3) * NN + i0 + (k & 7)];
  __syncthreads();

  const float4* __restrict__ Y4 = (const float4*)zy;
  const int yb = (j0 >> 2) + c;
  float4 acc = make_float4(0.f, 0.f, 0.f, 0.f);
  #pragma unroll 8
  for (int d = 0; d < DD; ++d) {
    const float4 yv = Y4[d * NQ + yb];
    const float xv = xs[d * 8 + rg];
    acc.x += fabsf(xv - yv.x);
    acc.y += fabsf(xv - yv.y);
    acc.z += fabsf(xv - yv.z);
    acc.w += fabsf(xv - yv.w);
  }

  const int i = i0 + rg;
  const float rm = rmax[i];
  const float ri = 1.f / rsum[i];
  const float4 cm = ((const float4*)cmax)[yb];
  const float4 cs = ((const float4*)csum)[yb];

  float un = 0.f, ud = 0.f;
  {
    const float s = -acc.x;
    const float a = __expf(s - rm) * ri;
    const float b = __expf(s - cm.x) / cs.x;
    const float u = a + b - a * b;
    un += u * s; ud += u;
  }
  {
    const float s = -acc.y;
    const float a = __expf(s - rm) * ri;
    const float b = __expf(s - cm.y) / cs.y;
    const float u = a + b - a * b;
    un += u * s; ud += u;
  }
  {
    const float s = -acc.z;
    const float a = __expf(s - rm) * ri;
    const float b = __expf(s - cm.z) / cs.z;
    const float u = a + b - a * b;
    un += u * s; ud += u;
  }
  {
    const float s = -acc.w;
    const float a = __expf(s - rm) * ri;
    const float b = __expf(s - cm.w) / cs.w;
    const float u = a + b - a * b;
    un += u * s; ud += u;
  }

  un = waveSum(un); ud = waveSum(ud);
  if ((t & 63) == 0) { redn[t >> 6] = un; redd[t >> 6] = ud; }
  __syncthreads();
  if (t == 0) {
    atomicAdd(&accum[0], redn[0] + redn[1] + redn[2] + redn[3]);
    atomicAdd(&accum[1], redd[0] + redd[1] + redd[2] + redd[3]);
  }
}

__global__ void finalize_kernel(const float* __restrict__ accum, float* __restrict__ out) {
  out[0] = accum[0] / accum[1];
}

// ---------------------------------------------------------------------------

extern "C" void kernel_launch(void* const* d_in, const int* in_sizes, int n_in,
                              void* d_out, int out_size, void* d_ws, size_t ws_size,
                              hipStream_t stream) {
  const float* zx = (const float*)d_in[0];   // (1, D, N): X[d*N + i]
  const float* zy = (const float*)d_in[1];   // (1, D, M): Y[d*M + j]
  float* ws  = (float*)d_ws;
  float* out = (float*)d_out;

  // fast-path ws layout (floats): ~4.8 MB
  float* accum = ws;                         // [0]=num, [1]=den, [2]=ticket
  float* S     = ws + 16;                    // 1M floats (4 MB)
  float* pRM   = S + NN * NN;                // 8 * 1024
  float* pRL   = pRM + 8 * NN;
  float* pCM   = pRL + 8 * NN;               // 64 * 1024
  float* pCL   = pCM + 64 * NN;
  float* rmax  = pCL + 64 * NN;
  float* rsum  = rmax + NN;
  float* cmax  = rsum + NN;
  float* csum  = cmax + NN;
  const size_t need = (size_t)((csum + NN) - ws) * sizeof(float);

  if (ws_size >= need) {
    dim3 g1(8, 64);                          // 512 blocks
    scompute_kernel<<<g1, 256, 0, stream>>>(zx, zy, S, pRM, pRL, pCM, pCL);
    combine_kernel<<<20, 256, 0, stream>>>(pRM, pRL, pCM, pCL,
                                           rmax, rsum, cmax, csum, accum);
    final_kernel<<<NN / 2, 256, 0, stream>>>(S, rmax, rsum, cmax, csum, accum, out);
  } else {
    // R2 fallback (~148 KB)
    float* partM = ws + 16;
    float* partS = partM + 2 * NCH * NN;
    float* frmax = partS + 2 * NCH * NN;
    float* frsum = frmax + NN;
    float* fcmax = frsum + NN;
    float* fcsum = fcmax + NN;
    dim3 sgrid(NCH, NN / 8, 2);
    stats2_kernel<<<sgrid, BLK, 0, stream>>>(zx, zy, partM, partS);
    combine_kernel_fb<<<(2 * NN) / BLK, BLK, 0, stream>>>(partM, partS,
                                                          frmax, frsum, fcmax, fcsum, accum);
    dim3 fgrid(NCH, NN / 8);
    final2_kernel<<<fgrid, BLK, 0, stream>>>(zx, zy, frmax, frsum, fcmax, fcsum, accum);
    finalize_kernel<<<1, 1, 0, stream>>>(accum, out);
  }
}